// Round 14
// baseline (53.605 us; speedup 1.0000x reference)
//
#include <hip/hip_runtime.h>

// Batched Thomas tridiagonal solve, B=8192 rows, N=4096.
//   a_i = alpha[i-1]^2 (a_0=0); b_i = max(5+alpha[i]^3, 0.01);
//   c_i = alpha[i+1]^2 + 2*alpha[i+1]; rhs f (shared across rows).
//
// Chunked UL elimination with halos (right halo 8, left halo 8; bounds give
// worst-case halo error ~5e-7 / 8e-6 vs threshold 2.25e-2).
//
// R14: dual-tile ILP. R4-R13 eliminated stores/conflicts/occupancy/work as
// limiters; residual = per-wave serial STEP chain (~16-20 cyc each) at 2
// resident waves/SIMD. The wave's two tiles are now solved INTERLEAVED (both
// panels in LDS, groups alternate tile0/tile1) -> two independent chains
// double issue utilization. Branch-free body: tile0 never-last, tile1
// never-first; tile1 last-lanes run halo on staged duplicates then ec/gc
// zeroed by cndmask. Per-tile math identical (absmax anchor 0.0078125).

namespace {
constexpr int kCH  = 32;
constexpr int kHL  = 8;
constexpr int kR   = kCH + kHL;       // 40
constexpr int RPW  = 8;
constexpr int WAVES = 2;
constexpr int THREADS = 64 * WAVES;   // 128
constexpr int F4PR = 69;              // staged f4/row: cols [cb-12, cb+264)
constexpr int ST4  = 71;              // panel row stride in f4
constexpr int APW4 = RPW * ST4;       // 568 f4 per panel
constexpr int SF4  = 133;             // shared f pair window
}

using f4v = float __attribute__((ext_vector_type(4)));

__global__ __launch_bounds__(THREADS, 2) void thomas_v14(
    const float4* __restrict__ alpha4,
    const float4* __restrict__ f4,
    float4* __restrict__ u4)
{
  __shared__ float4 sM[WAVES * 2 * APW4 + SF4];   // 2405 f4 = 38480 B

  const int bid  = blockIdx.x;
  const int pair = bid & 7;
  const int r0   = (bid >> 3) * (WAVES * RPW);
  const int w    = threadIdx.x >> 6;
  const int lane = threadIdx.x & 63;
  const int rw0  = r0 + w * RPW;
  const int j    = lane & 7;                    // row-local
  const int q    = lane >> 3;                   // chunk-local 0..7

  float4* __restrict__ sA0 = sM + w * (2 * APW4);   // tile0 panel [RPW][ST4]
  float4* __restrict__ sA1 = sA0 + APW4;            // tile1 panel
  float4* __restrict__ sF  = sM + WAVES * 2 * APW4; // block-shared f window

#define LOAD_TILE(cw, P)                                              \
  {                                                                   \
    const int cb4 = (cw) * 64 - 3;                                    \
    _Pragma("unroll")                                                 \
    for (int it = 0; it < 9; ++it) {                                  \
      int idx = lane + it * 64;                                       \
      if (idx > RPW * F4PR - 1) idx = RPW * F4PR - 1;                 \
      const int row = idx / F4PR;                                     \
      const int c4  = idx - row * F4PR;                               \
      int g4 = cb4 + c4;                                              \
      g4 = (g4 < 0) ? 0 : ((g4 > 1023) ? 1023 : g4);                  \
      P[it] = alpha4[(size_t)(rw0 + row) * 1024 + g4];                \
    }                                                                 \
  }

#define WRITE_TILE(P, SA)                                             \
  {                                                                   \
    _Pragma("unroll")                                                 \
    for (int it = 0; it < 9; ++it) {                                  \
      const int idx = lane + it * 64;                                 \
      if (idx < RPW * F4PR) {                                         \
        const int row = idx / F4PR;                                   \
        const int c4  = idx - row * F4PR;                             \
        (SA)[row * ST4 + c4] = P[it];                                 \
      }                                                               \
    }                                                                 \
  }

#define STEPX(ecv, gcv, ap1v, a0v, am1v, fiv)                    \
  {                                                              \
    const float c_  = ap1v * (ap1v + 2.0f);                      \
    const float b_  = fmaxf(fmaf(a0v * a0v, a0v, 5.0f), 0.01f);  \
    const float dn  = fmaf(-c_, ecv, b_);                        \
    const float rd  = __builtin_amdgcn_rcpf(dn);                 \
    gcv = (fiv - c_ * gcv) * rd;                                 \
    ecv = ((am1v) * (am1v)) * rd;                                \
    ap1v = a0v; a0v = (am1v);                                    \
  }

  // ---- shared f window (idempotent writes by both waves; no barrier) ----
  {
    const int fb4 = pair * 128 - 3;
    #pragma unroll
    for (int it = 0; it < 3; ++it) {
      const int idx = lane + it * 64;
      if (idx < SF4) {
        int g4 = fb4 + idx;
        g4 = (g4 < 0) ? 0 : ((g4 > 1023) ? 1023 : g4);
        sF[idx] = f4[g4];
      }
    }
  }

  // ---- stage both panels ----
  float4 p0[9], p1[9];
  LOAD_TILE(pair * 2,     p0)
  LOAD_TILE(pair * 2 + 1, p1)
  WRITE_TILE(p0, sA0)
  WRITE_TILE(p1, sA1)

  // ---- dual-tile interleaved solve ----
  const bool first0 = (pair == 0) && (q == 0);       // kk0 = pair*16+q
  const bool last1  = (pair == 7) && (q == 7);       // kk1 = pair*16+8+q
  const int  f4b0   = first0 ? 3 : (q * 8 + 1);
  const int  f4b1   = q * 8 + 1;

  const float4* __restrict__ A40 = sA0 + j * ST4;
  const float4* __restrict__ A41 = sA1 + j * ST4;

  float gp0[kR], ep0[kR], gp1[kR], ep1[kR];
  float ec0 = 0.0f, gc0 = 0.0f, ap10 = 0.0f;
  float ec1 = 0.0f, gc1 = 0.0f, ap11 = 0.0f;

  float4 curA0 = A40[f4b0 + 11], lowA0 = A40[f4b0 + 10];
  float4 fcur0 = sF[f4b0 + 11],  flow0 = sF[f4b0 + 10];
  float4 curA1 = A41[f4b1 + 11], lowA1 = A41[f4b1 + 10];
  float4 fcur1 = sF[64 + f4b1 + 11], flow1 = sF[64 + f4b1 + 10];
  float a00 = curA0.w, a01 = curA1.w;

  // Halo: groups 11,10 for BOTH tiles (tile1 last-lanes compute on staged
  // duplicates; zeroed after).
  #pragma unroll
  for (int g = 11; g >= 10; --g) {
    const float4 pA0 = A40[f4b0 + g - 2];
    const float4 pF0 = sF[f4b0 + g - 2];
    const float4 pA1 = A41[f4b1 + g - 2];
    const float4 pF1 = sF[64 + f4b1 + g - 2];
    STEPX(ec0, gc0, ap10, a00, curA0.z, fcur0.w)
    STEPX(ec1, gc1, ap11, a01, curA1.z, fcur1.w)
    STEPX(ec0, gc0, ap10, a00, curA0.y, fcur0.z)
    STEPX(ec1, gc1, ap11, a01, curA1.y, fcur1.z)
    STEPX(ec0, gc0, ap10, a00, curA0.x, fcur0.y)
    STEPX(ec1, gc1, ap11, a01, curA1.x, fcur1.y)
    STEPX(ec0, gc0, ap10, a00, lowA0.w, fcur0.x)
    STEPX(ec1, gc1, ap11, a01, lowA1.w, fcur1.x)
    curA0 = lowA0; lowA0 = pA0; fcur0 = flow0; flow0 = pF0;
    curA1 = lowA1; lowA1 = pA1; fcur1 = flow1; flow1 = pF1;
  }
  if (last1) { ec1 = 0.0f; gc1 = 0.0f; }   // true last tile: zero carry
                                           // (ap11 garbage nullified by c_*0)

  // Stored sweep: groups 9..0, both tiles interleaved.
  #pragma unroll
  for (int g = 9; g >= 0; --g) {
    int pi0 = f4b0 + g - 2; if (pi0 < 0) pi0 = 0;
    int pi1 = f4b1 + g - 2; if (pi1 < 0) pi1 = 0;
    const float4 pA0 = A40[pi0];
    const float4 pF0 = sF[pi0];
    const float4 pA1 = A41[pi1];
    const float4 pF1 = sF[64 + pi1];
    float lw0 = lowA0.w;
    if (g == 0 && first0) lw0 = 0.0f;      // a_0 = 0
    const float lw1 = lowA1.w;             // tile1 never first
    STEPX(ec0, gc0, ap10, a00, curA0.z, fcur0.w)  gp0[4*g+3] = gc0; ep0[4*g+3] = ec0;
    STEPX(ec1, gc1, ap11, a01, curA1.z, fcur1.w)  gp1[4*g+3] = gc1; ep1[4*g+3] = ec1;
    STEPX(ec0, gc0, ap10, a00, curA0.y, fcur0.z)  gp0[4*g+2] = gc0; ep0[4*g+2] = ec0;
    STEPX(ec1, gc1, ap11, a01, curA1.y, fcur1.z)  gp1[4*g+2] = gc1; ep1[4*g+2] = ec1;
    STEPX(ec0, gc0, ap10, a00, curA0.x, fcur0.y)  gp0[4*g+1] = gc0; ep0[4*g+1] = ec0;
    STEPX(ec1, gc1, ap11, a01, curA1.x, fcur1.y)  gp1[4*g+1] = gc1; ep1[4*g+1] = ec1;
    STEPX(ec0, gc0, ap10, a00, lw0,     fcur0.x)  gp0[4*g+0] = gc0; ep0[4*g+0] = ec0;
    STEPX(ec1, gc1, ap11, a01, lw1,     fcur1.x)  gp1[4*g+0] = gc1; ep1[4*g+0] = ec1;
    curA0 = lowA0; lowA0 = pA0; fcur0 = flow0; flow0 = pF0;
    curA1 = lowA1; lowA1 = pA1; fcur1 = flow1; flow1 = pF1;
  }

  // Substitution: both 40-step chains interleaved; pack float4, store to LDS.
  const int tmin0 = first0 ? 0 : kHL;
  const int tmin1 = kHL;
  float up0 = 0.0f, up1 = 0.0f;
  float4 pk0, pk1;
  #pragma unroll
  for (int t = 0; t < kR; ++t) {
    const float uv0 = fmaf(-ep0[t], up0, gp0[t]); up0 = uv0;
    const float uv1 = fmaf(-ep1[t], up1, gp1[t]); up1 = uv1;
    const int ph = t & 3;
    if (ph == 0) { pk0.x = uv0; pk1.x = uv1; }
    else if (ph == 1) { pk0.y = uv0; pk1.y = uv1; }
    else if (ph == 2) { pk0.z = uv0; pk1.z = uv1; }
    else {
      pk0.w = uv0; pk1.w = uv1;
      if (t - 3 >= tmin0 && t < tmin0 + kCH)
        sA0[j * ST4 + q * 8 + ((t - 3 - tmin0) >> 2)] = pk0;
      if (t - 3 >= tmin1 && t < tmin1 + kCH)
        sA1[j * ST4 + q * 8 + ((t - 3 - tmin1) >> 2)] = pk1;
    }
  }

  // ---- coalesced non-temporal dump: both tiles ----
  #pragma unroll
  for (int it = 0; it < RPW; ++it) {
    const float4 v0 = sA0[it * ST4 + lane];
    const float4 v1 = sA1[it * ST4 + lane];
    f4v vv0; vv0.x = v0.x; vv0.y = v0.y; vv0.z = v0.z; vv0.w = v0.w;
    f4v vv1; vv1.x = v1.x; vv1.y = v1.y; vv1.z = v1.z; vv1.w = v1.w;
    const size_t rb = (size_t)(rw0 + it) * 1024;
    __builtin_nontemporal_store(vv0,
        reinterpret_cast<f4v*>(u4 + rb + (pair * 2)     * 64 + lane));
    __builtin_nontemporal_store(vv1,
        reinterpret_cast<f4v*>(u4 + rb + (pair * 2 + 1) * 64 + lane));
  }

#undef LOAD_TILE
#undef WRITE_TILE
#undef STEPX
}

extern "C" void kernel_launch(void* const* d_in, const int* in_sizes, int n_in,
                              void* d_out, int out_size, void* d_ws, size_t ws_size,
                              hipStream_t stream) {
  const float4* alpha = (const float4*)d_in[0];
  const float4* f     = (const float4*)d_in[1];
  float4*       uo    = (float4*)d_out;
  // grid: 512 row-groups (16 rows) x 8 window-pairs (512 cols) = 4096 blocks
  thomas_v14<<<dim3(4096), THREADS, 0, stream>>>(alpha, f, uo);
}